// Round 2
// baseline (2478.767 us; speedup 1.0000x reference)
//
#include <hip/hip_runtime.h>

#define B_    16
#define C_    256
#define HW_   4096
#define CHW_  1048576
#define N_    65536
#define K_    1024
#define FLT_BIG 3.402823466e38f
#define GAP_T  6e-5f   // > 2*ulp(512)=6.1e-5? ulp(511)=3.05e-5; 2 steps = 6.1e-5; add slack below
// NOTE: flag threshold must exceed 2 quantization steps (worst ulp 3.05e-5 at |d|<512)
// plus fp32 scoring noise (~1e-7). 6e-5 is marginal; use 8e-5 for safety.
#undef GAP_T
#define GAP_T  8e-5f

// ---------------------------------------------------------------------------
// Kernel: s_z[n] = np.sum(zf*zf, axis=1) replicated in numpy pairwise order
// (n=256: two 128-blocks, each 8 strided accumulators, then fixed combine).
// fp contract OFF so each square rounds before the add, exactly like numpy.
// ---------------------------------------------------------------------------
__global__ void sz_kernel(const float* __restrict__ z, float* __restrict__ sz) {
#pragma clang fp contract(off)
    int n = blockIdx.x * 256 + threadIdx.x;
    const float* zp = z + (size_t)(n >> 12) * CHW_ + (n & 4095);
    float blk[2];
    for (int h = 0; h < 2; h++) {
        const float* p = zp + (size_t)(h * 128) * HW_;
        float r[8];
#pragma unroll
        for (int j = 0; j < 8; j++) { float v = p[(size_t)j * HW_]; r[j] = v * v; }
        for (int i = 8; i < 128; i += 8) {
#pragma unroll
            for (int j = 0; j < 8; j++) { float v = p[(size_t)(i + j) * HW_]; r[j] += v * v; }
        }
        blk[h] = ((r[0] + r[1]) + (r[2] + r[3])) + ((r[4] + r[5]) + (r[6] + r[7]));
    }
    sz[n] = blk[0] + blk[1];
}

// ---------------------------------------------------------------------------
// Kernel: s_c[k] = np.sum(cb*cb, axis=1), same numpy pairwise replication.
// ---------------------------------------------------------------------------
__global__ void sc_kernel(const float* __restrict__ cb, float* __restrict__ sc) {
#pragma clang fp contract(off)
    int k = blockIdx.x * 256 + threadIdx.x;
    const float* p0 = cb + (size_t)k * C_;
    float blk[2];
    for (int h = 0; h < 2; h++) {
        const float* p = p0 + h * 128;
        float r[8];
#pragma unroll
        for (int j = 0; j < 8; j++) { float v = p[j]; r[j] = v * v; }
        for (int i = 8; i < 128; i += 8) {
#pragma unroll
            for (int j = 0; j < 8; j++) { float v = p[i + j]; r[j] += v * v; }
        }
        blk[h] = ((r[0] + r[1]) + (r[2] + r[3])) + ((r[4] + r[5]) + (r[6] + r[7]));
    }
    sc[k] = blk[0] + blk[1];
}

// ---------------------------------------------------------------------------
// Main fp32 scoring: block = 64 pixels (64KB z-tile in LDS), 16x16 threads,
// tx->4 codes, ty->4 pixels, K in 16 tiles of 64.  Codebook read from global
// (L2-resident).  Tracks per-pixel top-2 (score, idx) for the gap test.
// score = s_c[k] - 2*dot (the ||z||^2 row constant doesn't affect ranking).
// ---------------------------------------------------------------------------
__global__ __launch_bounds__(256, 2)
void score_kernel(const float* __restrict__ z, const float* __restrict__ cb,
                  const float* __restrict__ sc,
                  float* __restrict__ s1o, float* __restrict__ s2o,
                  int* __restrict__ i1o) {
    __shared__ float zs[C_ * 64];
    int t   = threadIdx.x;
    int blk = blockIdx.x;
    int n0  = blk * 64;
    const float* zbase = z + (size_t)(n0 >> 12) * CHW_ + (n0 & 4095);

#pragma unroll
    for (int r = 0; r < 16; r++) {
        int f = r * 256 + t;
        int c = f >> 4, i4 = f & 15;
        float4 v = *(const float4*)(zbase + (size_t)c * HW_ + i4 * 4);
        *(float4*)(&zs[c * 64 + i4 * 4]) = v;
    }
    __syncthreads();

    int tx = t & 15, ty = t >> 4;
    const float* zrow = &zs[ty * 4];

    float b1[4], b2[4];
    int   j1[4], j2[4];
#pragma unroll
    for (int p = 0; p < 4; p++) { b1[p] = FLT_BIG; b2[p] = FLT_BIG; j1[p] = 0; j2[p] = 0; }

    for (int kt = 0; kt < 16; kt++) {
        int k0 = kt * 64 + tx * 4;
        const float* cbp = cb + (size_t)k0 * C_;
        float acc[4][4];
#pragma unroll
        for (int p = 0; p < 4; p++)
#pragma unroll
            for (int q = 0; q < 4; q++) acc[p][q] = 0.f;

#pragma unroll 2
        for (int c4 = 0; c4 < 64; c4++) {
            float4 bq[4];
#pragma unroll
            for (int q = 0; q < 4; q++)
                bq[q] = *(const float4*)(cbp + q * C_ + c4 * 4);
            float4 aj[4];
#pragma unroll
            for (int j = 0; j < 4; j++)
                aj[j] = *(const float4*)(&zrow[(c4 * 4 + j) * 64]);
#pragma unroll
            for (int j = 0; j < 4; j++) {
#pragma unroll
                for (int q = 0; q < 4; q++) {
                    float bv = (&bq[q].x)[j];
                    acc[0][q] += aj[j].x * bv;
                    acc[1][q] += aj[j].y * bv;
                    acc[2][q] += aj[j].z * bv;
                    acc[3][q] += aj[j].w * bv;
                }
            }
        }
#pragma unroll
        for (int q = 0; q < 4; q++) {
            int k = k0 + q;
            float cs = sc[k];
#pragma unroll
            for (int p = 0; p < 4; p++) {
                float s = fmaf(-2.f, acc[p][q], cs);
                if (s < b1[p]) { b2[p] = b1[p]; j2[p] = j1[p]; b1[p] = s; j1[p] = k; }
                else if (s < b2[p]) { b2[p] = s; j2[p] = k; }
            }
        }
    }

#pragma unroll
    for (int off = 1; off < 16; off <<= 1) {
#pragma unroll
        for (int p = 0; p < 4; p++) {
            float ob1 = __shfl_xor(b1[p], off, 64);
            int   oj1 = __shfl_xor(j1[p], off, 64);
            float ob2 = __shfl_xor(b2[p], off, 64);
            int   oj2 = __shfl_xor(j2[p], off, 64);
            if (ob1 < b1[p] || (ob1 == b1[p] && oj1 < j1[p])) {
                float nb2; int nj2;
                if (b1[p] < ob2 || (b1[p] == ob2 && j1[p] < oj2)) { nb2 = b1[p]; nj2 = j1[p]; }
                else                                              { nb2 = ob2;  nj2 = oj2;  }
                b1[p] = ob1; j1[p] = oj1; b2[p] = nb2; j2[p] = nj2;
            } else if (ob1 < b2[p] || (ob1 == b2[p] && oj1 < j2[p])) {
                b2[p] = ob1; j2[p] = oj1;
            }
        }
    }

    if (tx == 0) {
#pragma unroll
        for (int p = 0; p < 4; p++) {
            int n = n0 + ty * 4 + p;
            s1o[n] = b1[p]; s2o[n] = b2[p]; i1o[n] = j1[p];
        }
    }
}

// ---------------------------------------------------------------------------
// Flag pass: commit clear winners; compact near-tie pixels into a list.
// ---------------------------------------------------------------------------
__global__ void flag_kernel(const float* __restrict__ s1, const float* __restrict__ s2,
                            const int* __restrict__ i1,
                            int* __restrict__ fidx, float* __restrict__ out_idx,
                            int* __restrict__ list, int* __restrict__ count) {
    int n = blockIdx.x * 256 + threadIdx.x;
    int j = i1[n];
    fidx[n] = j;
    out_idx[n] = (float)j;
    if (s2[n] - s1[n] < GAP_T) {
        int pos = atomicAdd(count, 1);
        list[pos] = n;
    }
}

// ---------------------------------------------------------------------------
// Exact refine: one wave per flagged pixel, re-scan all 1024 codes with the
// reference's exact quantized-fp32 arithmetic:
//   d_q[k] = fp32( fp32(s_z[n] + s_c[k]) - 2*fp32(dot_exact) ),
// first-index argmin (replicates np.argmin on the quantized distances).
// ---------------------------------------------------------------------------
__global__ void refine_kernel(const float* __restrict__ z, const float* __restrict__ cb,
                              const float* __restrict__ sz, const float* __restrict__ sc,
                              const int* __restrict__ list, const int* __restrict__ count,
                              int* __restrict__ fidx, float* __restrict__ out_idx) {
    int lane = threadIdx.x & 63;
    int wid  = blockIdx.x * 4 + (threadIdx.x >> 6);
    int cnt  = *count;
    for (int ii = wid; ii < cnt; ii += 1024) {
        int n = list[ii];
        const float* zp = z + (size_t)(n >> 12) * CHW_ + (n & 4095);
        double zd[4];
#pragma unroll
        for (int j = 0; j < 4; j++) zd[j] = (double)zp[(size_t)(lane * 4 + j) * HW_];
        float szv = sz[n];
        float best = FLT_BIG; int bidx = 0;
        for (int k = 0; k < K_; k++) {
            float4 cv = *(const float4*)(cb + (size_t)k * C_ + lane * 4);
            double part = zd[0] * (double)cv.x + zd[1] * (double)cv.y
                        + zd[2] * (double)cv.z + zd[3] * (double)cv.w;
#pragma unroll
            for (int off = 32; off > 0; off >>= 1) part += __shfl_xor(part, off, 64);
            float dotf = (float)part;        // ref's dot is an fp32 value
            float S    = szv + sc[k];        // ref rounds (s_z + s_c) first
            float dq   = S - 2.0f * dotf;    // then one more fp32 rounding
            if (dq < best) { best = dq; bidx = k; }   // strict < => first min
        }
        if (lane == 0) { fidx[n] = bidx; out_idx[n] = (float)bidx; }
    }
}

// ---------------------------------------------------------------------------
// Gather zq -> NCHW output (coalesced stores) + loss partials
// ---------------------------------------------------------------------------
__global__ void output_kernel(const float* __restrict__ z, const float* __restrict__ cb,
                              const int* __restrict__ fidx,
                              float* __restrict__ out0, double* __restrict__ partials) {
    __shared__ double red[256];
    int t = threadIdx.x;
    int blk = blockIdx.x;
    int n0 = blk * 64;
    int batch = n0 >> 12, s0 = n0 & 4095;
    const float* zbase = z + (size_t)batch * CHW_ + s0;
    float* obase = out0 + (size_t)batch * CHW_ + s0;
    double sum = 0.0;
#pragma unroll 4
    for (int r = 0; r < 64; r++) {
        int f = r * 256 + t;
        int c = f >> 6, i = f & 63;
        int idx = fidx[n0 + i];
        float q  = cb[(size_t)idx * C_ + c];
        float zv = zbase[(size_t)c * HW_ + i];
        obase[(size_t)c * HW_ + i] = q;
        float d = q - zv;
        sum += (double)d * (double)d;
    }
    red[t] = sum;
    __syncthreads();
    for (int s = 128; s > 0; s >>= 1) {
        if (t < s) red[t] += red[t + s];
        __syncthreads();
    }
    if (t == 0) partials[blk] = red[0];
}

__global__ void loss_kernel(const double* __restrict__ partials, float* __restrict__ out_loss) {
    __shared__ double red[256];
    int t = threadIdx.x;
    double s = 0.0;
    for (int r = t; r < 1024; r += 256) s += partials[r];
    red[t] = s;
    __syncthreads();
    for (int k = 128; k > 0; k >>= 1) {
        if (t < k) red[t] += red[t + k];
        __syncthreads();
    }
    if (t == 0) *out_loss = (float)(0.75 * red[0] / 16777216.0);
}

// ---------------------------------------------------------------------------
extern "C" void kernel_launch(void* const* d_in, const int* in_sizes, int n_in,
                              void* d_out, int out_size, void* d_ws, size_t ws_size,
                              hipStream_t stream) {
    const float* z  = (const float*)d_in[0];
    const float* cb = (const float*)d_in[1];

    float* out0     = (float*)d_out;
    float* out_idx  = out0 + (size_t)16777216;
    float* out_loss = out0 + (size_t)16842752;

    char* w = (char*)d_ws;
    double* partials = (double*)w;                        // 8192 B
    float*  sc   = (float*)(w + 8192);                    // 4096 B
    float*  sz   = (float*)(w + 12288);                   // 256 KB
    float*  s1   = (float*)(w + 12288 + 1 * 262144);
    float*  s2   = (float*)(w + 12288 + 2 * 262144);
    int*    i1   = (int*)  (w + 12288 + 3 * 262144);
    int*    fidx = (int*)  (w + 12288 + 4 * 262144);
    int*    count= (int*)  (w + 12288 + 5 * 262144);      // 4 B (+pad)
    int*    list = (int*)  (w + 12288 + 5 * 262144 + 256);// 256 KB
    // total ~1.57 MB

    hipMemsetAsync(count, 0, 4, stream);
    sz_kernel    <<<256,  256, 0, stream>>>(z, sz);
    sc_kernel    <<<4,    256, 0, stream>>>(cb, sc);
    score_kernel <<<1024, 256, 0, stream>>>(z, cb, sc, s1, s2, i1);
    flag_kernel  <<<256,  256, 0, stream>>>(s1, s2, i1, fidx, out_idx, list, count);
    refine_kernel<<<256,  256, 0, stream>>>(z, cb, sz, sc, list, count, fidx, out_idx);
    output_kernel<<<1024, 256, 0, stream>>>(z, cb, fidx, out0, partials);
    loss_kernel  <<<1,    256, 0, stream>>>(partials, out_loss);
}

// Round 4
// 563.693 us; speedup vs baseline: 4.3974x; 4.3974x over previous
//
#include <hip/hip_runtime.h>

#define B_    16
#define C_    256
#define HW_   4096
#define CHW_  1048576
#define N_    65536
#define K_    1024
#define FLT_BIG 3.402823466e38f
#define GAP_T  3.2e-4f   // bf16-split score error (sigma ~2.3e-5, 14-sigma) + ref fp32 quantization

typedef __attribute__((ext_vector_type(8)))  short  short8;
typedef __attribute__((ext_vector_type(16))) float  float16;

__device__ __forceinline__ unsigned rne_bf16(float v) {
    unsigned u = __float_as_uint(v);
    return (u + 0x7fffu + ((u >> 16) & 1u)) >> 16;
}

// ---------------------------------------------------------------------------
// s_z[n] numpy pairwise order (PASSED round 2 - do not touch)
// ---------------------------------------------------------------------------
__global__ void sz_kernel(const float* __restrict__ z, float* __restrict__ sz) {
#pragma clang fp contract(off)
    int n = blockIdx.x * 256 + threadIdx.x;
    const float* zp = z + (size_t)(n >> 12) * CHW_ + (n & 4095);
    float blk[2];
    for (int h = 0; h < 2; h++) {
        const float* p = zp + (size_t)(h * 128) * HW_;
        float r[8];
#pragma unroll
        for (int j = 0; j < 8; j++) { float v = p[(size_t)j * HW_]; r[j] = v * v; }
        for (int i = 8; i < 128; i += 8) {
#pragma unroll
            for (int j = 0; j < 8; j++) { float v = p[(size_t)(i + j) * HW_]; r[j] += v * v; }
        }
        blk[h] = ((r[0] + r[1]) + (r[2] + r[3])) + ((r[4] + r[5]) + (r[6] + r[7]));
    }
    sz[n] = blk[0] + blk[1];
}

// ---------------------------------------------------------------------------
// s_c[k] numpy pairwise order (PASSED round 2)
// ---------------------------------------------------------------------------
__global__ void sc_kernel(const float* __restrict__ cb, float* __restrict__ sc) {
#pragma clang fp contract(off)
    int k = blockIdx.x * 256 + threadIdx.x;
    const float* p0 = cb + (size_t)k * C_;
    float blk[2];
    for (int h = 0; h < 2; h++) {
        const float* p = p0 + h * 128;
        float r[8];
#pragma unroll
        for (int j = 0; j < 8; j++) { float v = p[j]; r[j] = v * v; }
        for (int i = 8; i < 128; i += 8) {
#pragma unroll
            for (int j = 0; j < 8; j++) { float v = p[i + j]; r[j] += v * v; }
        }
        blk[h] = ((r[0] + r[1]) + (r[2] + r[3])) + ((r[4] + r[5]) + (r[6] + r[7]));
    }
    sc[k] = blk[0] + blk[1];
}

// ---------------------------------------------------------------------------
// Prep: codebook -> bf16 hi/lo, A-fragment-ordered image per K-step.
// Flat idx: (chunk*16+kk)*8192 + code*32 + h*8 + j  (hi at +0, lo at +16),
// k_global = chunk*256+code, channel = kk*16 + h*8 + j.
// ---------------------------------------------------------------------------
__global__ void cbf_prep(const float* __restrict__ cb, short* __restrict__ cbf) {
    int k = blockIdx.x, c = threadIdx.x;
    float v = cb[(size_t)k * C_ + c];
    unsigned hb = rne_bf16(v);
    float hf = __uint_as_float(hb << 16);
    unsigned lb = rne_bf16(v - hf);
    int chunk = k >> 8, code = k & 255, kk = c >> 4, h = (c >> 3) & 1, j = c & 7;
    size_t F = (size_t)(chunk * 16 + kk) * 8192 + code * 32 + h * 8 + j;
    cbf[F]      = (short)hb;
    cbf[F + 16] = (short)lb;
}

// Prep: cbT[c][k] = cb[k][c] fp32 (refine's coalesced per-lane-k loads)
__global__ void cbT_prep(const float* __restrict__ cb, float* __restrict__ cbT) {
    int c = blockIdx.x, k = threadIdx.x;
    cbT[(size_t)c * K_ + k] = cb[(size_t)k * C_ + c];
}

// ---------------------------------------------------------------------------
// MFMA score kernel, round 4: A-frags from GLOBAL (L2) with 2-step register
// prefetch (no A LDS, no in-loop barriers); z-tile in LDS with XOR swizzle
// (conflict-free b128 B-frag reads).  Block = 64 pixels, 4 waves; wave w
// covers codes w*64 + chunk*256, mt in {0,1} (32 codes each), nt pixels.
// C/D: col(pixel)=lane&31, row(code)=(r&3)+8*(r>>2)+4*(lane>>5) [HW-verified].
// ---------------------------------------------------------------------------
__global__ __launch_bounds__(256)
void score_kernel(const float* __restrict__ z, const short* __restrict__ cbf,
                  const float* __restrict__ sc,
                  float* __restrict__ s1o, float* __restrict__ s2o,
                  int* __restrict__ i1o) {
    __shared__ __align__(16) short zb[64 * 264];   // 64 px rows x 132 words (128 data + 4 pad), swizzled
    __shared__ float ex[256 * 4];                  // cross-wave merge buffer, 4 KB

    int t = threadIdx.x;
    int w = t >> 6, l = t & 63;
    int n0 = blockIdx.x * 64;

    // ---- stage z tile as packed bf16 pairs, XOR-swizzled 16B chunks ----
    {
        int p = t & 63, g = t >> 6;                // wave g handles word rem g
        const float* zp = z + (size_t)(n0 >> 12) * CHW_ + (n0 & 4095) + p;
        int key = (p >> 3) & 3;
        int* zw = (int*)zb;
#pragma unroll 4
        for (int i = 0; i < 32; i++) {
            int widx = i * 4 + g;                  // logical word in row [0,128)
            int c0 = widx * 2;
            float v0 = zp[(size_t)c0 * HW_];
            float v1 = zp[(size_t)(c0 + 1) * HW_];
            unsigned pk = rne_bf16(v0) | (rne_bf16(v1) << 16);
            zw[p * 132 + (((i ^ key) << 2) | g)] = pk;   // c16 = i, rem = g
        }
    }
    __syncthreads();

    float b1[2], b2[2];
    int   j1[2];
#pragma unroll
    for (int nt = 0; nt < 2; nt++) { b1[nt] = FLT_BIG; b2[nt] = FLT_BIG; j1[nt] = 0; }

    // A-frag global base for this lane: code row (w*64 + (l&31)), k-half (l>>5)
    const short8* ab = (const short8*)(cbf + ((size_t)(w * 64 + (l & 31)) * 32 + (l >> 5) * 8));
    // per step (1024 short8), mt stride 128 short8, lo at +2 short8
    short8 pf[2][4];
#pragma unroll
    for (int i = 0; i < 2; i++) {
        const short8* s = ab + (size_t)i * 1024;
        pf[i][0] = s[0]; pf[i][1] = s[2]; pf[i][2] = s[128]; pf[i][3] = s[130];
    }

    int bkey = (l & 31) >> 3;                      // B-read swizzle key
    int prow0 = (l & 31) * 132;

    for (int chunk = 0; chunk < 4; chunk++) {
        float16 acc[2][2];
#pragma unroll
        for (int mt = 0; mt < 2; mt++)
#pragma unroll
            for (int nt = 0; nt < 2; nt++)
#pragma unroll
                for (int r = 0; r < 16; r++) acc[mt][nt][r] = 0.f;

#pragma unroll
        for (int kk = 0; kk < 16; kk++) {
            int step = chunk * 16 + kk;
            int buf = step & 1;
            short8 a0h = pf[buf][0], a0l = pf[buf][1], a1h = pf[buf][2], a1l = pf[buf][3];
            int ns = step + 2; if (ns > 63) ns = 63;
            {   // prefetch step+2 into the buffer just consumed
                const short8* s = ab + (size_t)ns * 1024;
                pf[buf][0] = s[0]; pf[buf][1] = s[2]; pf[buf][2] = s[128]; pf[buf][3] = s[130];
            }
            short8 bz[2];
#pragma unroll
            for (int nt = 0; nt < 2; nt++) {
                int c16 = kk * 2 + (l >> 5);
                int word = (nt * 32 * 132 + prow0) + ((c16 ^ bkey) << 2);
                bz[nt] = *(const short8*)((const char*)zb + (size_t)word * 4);
            }
            acc[0][0] = __builtin_amdgcn_mfma_f32_32x32x16_bf16(a0h, bz[0], acc[0][0], 0, 0, 0);
            acc[0][1] = __builtin_amdgcn_mfma_f32_32x32x16_bf16(a0h, bz[1], acc[0][1], 0, 0, 0);
            acc[1][0] = __builtin_amdgcn_mfma_f32_32x32x16_bf16(a1h, bz[0], acc[1][0], 0, 0, 0);
            acc[1][1] = __builtin_amdgcn_mfma_f32_32x32x16_bf16(a1h, bz[1], acc[1][1], 0, 0, 0);
            acc[0][0] = __builtin_amdgcn_mfma_f32_32x32x16_bf16(a0l, bz[0], acc[0][0], 0, 0, 0);
            acc[0][1] = __builtin_amdgcn_mfma_f32_32x32x16_bf16(a0l, bz[1], acc[0][1], 0, 0, 0);
            acc[1][0] = __builtin_amdgcn_mfma_f32_32x32x16_bf16(a1l, bz[0], acc[1][0], 0, 0, 0);
            acc[1][1] = __builtin_amdgcn_mfma_f32_32x32x16_bf16(a1l, bz[1], acc[1][1], 0, 0, 0);
        }

        // fold chunk scores into per-lane top-2
#pragma unroll
        for (int mt = 0; mt < 2; mt++)
#pragma unroll
            for (int nt = 0; nt < 2; nt++)
#pragma unroll
                for (int r = 0; r < 16; r++) {
                    int code = chunk * 256 + w * 64 + mt * 32
                             + (r & 3) + ((r >> 2) << 3) + ((l >> 5) << 2);
                    float s = fmaf(-2.f, acc[mt][nt][r], sc[code]);
                    if (s < b1[nt]) { b2[nt] = b1[nt]; b1[nt] = s; j1[nt] = code; }
                    else if (s < b2[nt]) b2[nt] = s;
                }
    }

    // merge lane pairs (l, l^32): same pixel, disjoint code rows
#pragma unroll
    for (int nt = 0; nt < 2; nt++) {
        float ob1 = __shfl_xor(b1[nt], 32, 64);
        int   oj1 = __shfl_xor(j1[nt], 32, 64);
        float ob2 = __shfl_xor(b2[nt], 32, 64);
        if (ob1 < b1[nt] || (ob1 == b1[nt] && oj1 < j1[nt])) {
            b2[nt] = fminf(b1[nt], ob2); b1[nt] = ob1; j1[nt] = oj1;
        } else {
            b2[nt] = fminf(b2[nt], ob1);
        }
    }

    // cross-wave merge via dedicated ex buffer
    if (l < 32) {
#pragma unroll
        for (int nt = 0; nt < 2; nt++) {
            int e = w * 64 + nt * 32 + l;
            ex[e * 4 + 0] = b1[nt];
            ex[e * 4 + 1] = b2[nt];
            ((int*)ex)[e * 4 + 2] = j1[nt];
        }
    }
    __syncthreads();
    if (t < 64) {
        float cb1 = FLT_BIG, cb2 = FLT_BIG; int cj1 = 0;
#pragma unroll
        for (int wv = 0; wv < 4; wv++) {
            int e = wv * 64 + t;
            float nb1 = ex[e * 4 + 0];
            float nb2 = ex[e * 4 + 1];
            int   nj1 = ((int*)ex)[e * 4 + 2];
            if (nb1 < cb1 || (nb1 == cb1 && nj1 < cj1)) {
                cb2 = fminf(cb1, nb2); cb1 = nb1; cj1 = nj1;
            } else {
                cb2 = fminf(cb2, nb1);
            }
        }
        int n = n0 + t;
        s1o[n] = cb1; s2o[n] = cb2; i1o[n] = cj1;
    }
}

// ---------------------------------------------------------------------------
// Flag pass: commit clear winners; compact near-ties.
// ---------------------------------------------------------------------------
__global__ void flag_kernel(const float* __restrict__ s1, const float* __restrict__ s2,
                            const int* __restrict__ i1,
                            int* __restrict__ fidx, float* __restrict__ out_idx,
                            int* __restrict__ list, int* __restrict__ count) {
    int n = blockIdx.x * 256 + threadIdx.x;
    int j = i1[n];
    fidx[n] = j;
    out_idx[n] = (float)j;
    if (s2[n] - s1[n] < GAP_T) {
        int pos = atomicAdd(count, 1);
        list[pos] = n;
    }
}

// ---------------------------------------------------------------------------
// Exact refine: wave per flagged pixel, lane covers k = it*256 + 4*lane + s,
// fp64 dot, then reference-quantized fp32 (round-2-PASSED semantics):
//   dq = fp32( fp32(sz + sc[k]) - 2*fp32(dot) ), first-index argmin.
// ---------------------------------------------------------------------------
__global__ void refine_kernel(const float* __restrict__ z, const float* __restrict__ cbT,
                              const float* __restrict__ sz, const float* __restrict__ sc,
                              const int* __restrict__ list, const int* __restrict__ count,
                              int* __restrict__ fidx, float* __restrict__ out_idx) {
    __shared__ double zd[4][256];
    int w = threadIdx.x >> 6, l = threadIdx.x & 63;
    int cnt = *count;
    if (cnt > 65536) cnt = 65536;
    for (int ii = blockIdx.x * 4 + w; ii < cnt; ii += 1024) {
        int n = list[ii];
        const float* zp = z + (size_t)(n >> 12) * CHW_ + (n & 4095);
#pragma unroll
        for (int j = 0; j < 4; j++)
            zd[w][l * 4 + j] = (double)zp[(size_t)(l * 4 + j) * HW_];
        asm volatile("s_waitcnt lgkmcnt(0)" ::: "memory");  // cross-lane LDS visibility
        double acc[16];
#pragma unroll
        for (int a = 0; a < 16; a++) acc[a] = 0.0;
        for (int c = 0; c < 256; c++) {
            double zc = zd[w][c];
            const float* cp = cbT + (size_t)c * K_ + l * 4;
#pragma unroll
            for (int it = 0; it < 4; it++) {
                float4 cv = *(const float4*)(cp + it * 256);
                acc[it * 4 + 0] += zc * (double)cv.x;
                acc[it * 4 + 1] += zc * (double)cv.y;
                acc[it * 4 + 2] += zc * (double)cv.z;
                acc[it * 4 + 3] += zc * (double)cv.w;
            }
        }
        float szv = sz[n];
        float best = FLT_BIG; int bidx = K_;
#pragma unroll
        for (int it = 0; it < 4; it++)
#pragma unroll
            for (int s = 0; s < 4; s++) {
                int k = it * 256 + l * 4 + s;
                float dotf = (float)acc[it * 4 + s];
                float dq = (szv + sc[k]) - 2.0f * dotf;
                if (dq < best || (dq == best && k < bidx)) { best = dq; bidx = k; }
            }
#pragma unroll
        for (int off = 32; off > 0; off >>= 1) {
            float ob = __shfl_xor(best, off, 64);
            int   oj = __shfl_xor(bidx, off, 64);
            if (ob < best || (ob == best && oj < bidx)) { best = ob; bidx = oj; }
        }
        if (l == 0) { fidx[n] = bidx; out_idx[n] = (float)bidx; }
        asm volatile("s_waitcnt lgkmcnt(0)" ::: "memory");  // zd reads done before next ii overwrites
    }
}

// ---------------------------------------------------------------------------
// Gather zq -> NCHW output + loss partials (PASSED round 2)
// ---------------------------------------------------------------------------
__global__ void output_kernel(const float* __restrict__ z, const float* __restrict__ cb,
                              const int* __restrict__ fidx,
                              float* __restrict__ out0, double* __restrict__ partials) {
    __shared__ double red[256];
    int t = threadIdx.x;
    int blk = blockIdx.x;
    int n0 = blk * 64;
    int batch = n0 >> 12, s0 = n0 & 4095;
    const float* zbase = z + (size_t)batch * CHW_ + s0;
    float* obase = out0 + (size_t)batch * CHW_ + s0;
    double sum = 0.0;
#pragma unroll 4
    for (int r = 0; r < 64; r++) {
        int f = r * 256 + t;
        int c = f >> 6, i = f & 63;
        int idx = fidx[n0 + i];
        float q  = cb[(size_t)idx * C_ + c];
        float zv = zbase[(size_t)c * HW_ + i];
        obase[(size_t)c * HW_ + i] = q;
        float d = q - zv;
        sum += (double)d * (double)d;
    }
    red[t] = sum;
    __syncthreads();
    for (int s = 128; s > 0; s >>= 1) {
        if (t < s) red[t] += red[t + s];
        __syncthreads();
    }
    if (t == 0) partials[blk] = red[0];
}

__global__ void loss_kernel(const double* __restrict__ partials, float* __restrict__ out_loss) {
    __shared__ double red[256];
    int t = threadIdx.x;
    double s = 0.0;
    for (int r = t; r < 1024; r += 256) s += partials[r];
    red[t] = s;
    __syncthreads();
    for (int k = 128; k > 0; k >>= 1) {
        if (t < k) red[t] += red[t + k];
        __syncthreads();
    }
    if (t == 0) *out_loss = (float)(0.75 * red[0] / 16777216.0);
}

// ---------------------------------------------------------------------------
extern "C" void kernel_launch(void* const* d_in, const int* in_sizes, int n_in,
                              void* d_out, int out_size, void* d_ws, size_t ws_size,
                              hipStream_t stream) {
    const float* z  = (const float*)d_in[0];
    const float* cb = (const float*)d_in[1];

    float* out0     = (float*)d_out;
    float* out_idx  = out0 + (size_t)16777216;
    float* out_loss = out0 + (size_t)16842752;

    char* w = (char*)d_ws;
    double* partials = (double*)w;                    //       0 .. 8192
    float*  sc   = (float*)(w + 8192);                //    8192 .. 12288
    float*  sz   = (float*)(w + 12288);               //   12288 .. 274432
    float*  s1   = (float*)(w + 274432);
    float*  s2   = (float*)(w + 536576);
    int*    i1   = (int*)  (w + 798720);
    int*    fidx = (int*)  (w + 1060864);
    int*    count= (int*)  (w + 1323008);
    int*    list = (int*)  (w + 1323264);             // 256 KB
    short*  cbf  = (short*)(w + 1585408);             // 1 MB
    float*  cbT  = (float*)(w + 2633984);             // 1 MB

    hipMemsetAsync(count, 0, 4, stream);
    sz_kernel    <<<256,  256, 0, stream>>>(z, sz);
    sc_kernel    <<<4,    256, 0, stream>>>(cb, sc);
    cbf_prep     <<<1024, 256, 0, stream>>>(cb, cbf);
    cbT_prep     <<<256, 1024, 0, stream>>>(cb, cbT);
    score_kernel <<<1024, 256, 0, stream>>>(z, cbf, sc, s1, s2, i1);
    flag_kernel  <<<256,  256, 0, stream>>>(s1, s2, i1, fidx, out_idx, list, count);
    refine_kernel<<<256,  256, 0, stream>>>(z, cbT, sz, sc, list, count, fidx, out_idx);
    output_kernel<<<1024, 256, 0, stream>>>(z, cb, fidx, out0, partials);
    loss_kernel  <<<1,    256, 0, stream>>>(partials, out_loss);
}

// Round 5
// 320.988 us; speedup vs baseline: 7.7223x; 1.7561x over previous
//
#include <hip/hip_runtime.h>
#include <hip/hip_fp16.h>

#define B_    16
#define C_    256
#define HW_   4096
#define CHW_  1048576
#define N_    65536
#define K_    1024
#define FLT_BIG 3.402823466e38f
#define GAP_T  1.2e-4f   // ref fp32-quant floor 6.1e-5 + 6sigma fp16 score err ~3.1e-5 + key-pack 8e-6 + margin

typedef _Float16 half8 __attribute__((ext_vector_type(8)));
typedef float   float16 __attribute__((ext_vector_type(16)));

__device__ __forceinline__ unsigned umin_(unsigned a, unsigned b) { return a < b ? a : b; }
__device__ __forceinline__ unsigned umax_(unsigned a, unsigned b) { return a > b ? a : b; }

// ---------------------------------------------------------------------------
// s_z[n] numpy pairwise order (PASSED r2/r4 - do not touch)
// ---------------------------------------------------------------------------
__global__ void sz_kernel(const float* __restrict__ z, float* __restrict__ sz) {
#pragma clang fp contract(off)
    int n = blockIdx.x * 256 + threadIdx.x;
    const float* zp = z + (size_t)(n >> 12) * CHW_ + (n & 4095);
    float blk[2];
    for (int h = 0; h < 2; h++) {
        const float* p = zp + (size_t)(h * 128) * HW_;
        float r[8];
#pragma unroll
        for (int j = 0; j < 8; j++) { float v = p[(size_t)j * HW_]; r[j] = v * v; }
        for (int i = 8; i < 128; i += 8) {
#pragma unroll
            for (int j = 0; j < 8; j++) { float v = p[(size_t)(i + j) * HW_]; r[j] += v * v; }
        }
        blk[h] = ((r[0] + r[1]) + (r[2] + r[3])) + ((r[4] + r[5]) + (r[6] + r[7]));
    }
    sz[n] = blk[0] + blk[1];
}

// ---------------------------------------------------------------------------
// s_c[k] numpy pairwise order (PASSED r2/r4)
// ---------------------------------------------------------------------------
__global__ void sc_kernel(const float* __restrict__ cb, float* __restrict__ sc) {
#pragma clang fp contract(off)
    int k = blockIdx.x * 256 + threadIdx.x;
    const float* p0 = cb + (size_t)k * C_;
    float blk[2];
    for (int h = 0; h < 2; h++) {
        const float* p = p0 + h * 128;
        float r[8];
#pragma unroll
        for (int j = 0; j < 8; j++) { float v = p[j]; r[j] = v * v; }
        for (int i = 8; i < 128; i += 8) {
#pragma unroll
            for (int j = 0; j < 8; j++) { float v = p[i + j]; r[j] += v * v; }
        }
        blk[h] = ((r[0] + r[1]) + (r[2] + r[3])) + ((r[4] + r[5]) + (r[6] + r[7]));
    }
    sc[k] = blk[0] + blk[1];
}

// ---------------------------------------------------------------------------
// Prep: codebook -> fp16 (x1024 exact scale, avoids fp16 denormal band),
// A-fragment image per K-step.  Element: (kk*1024 + k)*16 + h*8 + j
// with channel c = kk*16 + h*8 + j.  512 KB, L2-resident.
// ---------------------------------------------------------------------------
__global__ void cbh_prep(const float* __restrict__ cb, unsigned short* __restrict__ cbh) {
    int k = blockIdx.x, c = threadIdx.x;
    float v = cb[(size_t)k * C_ + c] * 1024.0f;
    __half hv = __float2half_rn(v);
    size_t F = ((size_t)(c >> 4) * 1024 + k) * 16 + ((c >> 3) & 1) * 8 + (c & 7);
    cbh[F] = __half_as_ushort(hv);
}

// Prep: cbT[c][k] = cb[k][c] fp32 (refine's coalesced per-lane-k loads)
__global__ void cbT_prep(const float* __restrict__ cb, float* __restrict__ cbT) {
    int c = blockIdx.x, k = threadIdx.x;
    cbT[(size_t)c * K_ + k] = cb[(size_t)k * C_ + c];
}

// ---------------------------------------------------------------------------
// fp16 MFMA score kernel.  Block = 64 pixels, 256 thr (4 waves).
// Wave w covers codes chunk*256 + w*64 + mt*32 + (l&31), 4 chunks of 256.
// A-frags from global (L2) with depth-2 register prefetch - no in-loop
// barriers.  z tile fp16 in LDS, XOR-swizzled (conflict-free b128 reads).
// Scores shifted +0.25 (positive => uint-monotone); packed key =
// (asuint(s') & ~127) | (chunk<<5)|(mt<<4)|r  -> branchless top-2 via
// u32 min/max, first-index ties automatic.
// C/D: col(pixel)=lane&31, row(code)=(r&3)+8*(r>>2)+4*(lane>>5) [HW-verified].
// ---------------------------------------------------------------------------
__global__ __launch_bounds__(256, 4)
void score_kernel(const float* __restrict__ z, const unsigned short* __restrict__ cbh,
                  const float* __restrict__ sc,
                  float* __restrict__ s1o, float* __restrict__ s2o,
                  int* __restrict__ i1o) {
    __shared__ __align__(16) int zw[64 * 132];   // 64 px rows x 132 words (128 data + 4 pad), 33792 B
    __shared__ float scs[1024];                  // sc + 0.25, 4 KB
    __shared__ float ex[4 * 64 * 4];             // cross-wave merge, 4 KB

    int t = threadIdx.x;
    int w = t >> 6, l = t & 63;
    int n0 = blockIdx.x * 64;

    // stage shifted sc
    for (int i = t; i < 1024; i += 256) scs[i] = sc[i] + 0.25f;

    // stage z tile as packed fp16 pairs, XOR-swizzled 16B chunks.
    // thread (w,l): pixel px=l, channels [w*64, w*64+64)
    {
        int px = l;
        const float* zp = z + (size_t)(n0 >> 12) * CHW_ + (n0 & 4095) + px;
        int key = (px >> 3) & 3;
#pragma unroll 4
        for (int i = 0; i < 32; i++) {
            int widx = w * 32 + i;               // logical word in row [0,128)
            int c0 = widx * 2;
            float v0 = zp[(size_t)c0 * HW_];
            float v1 = zp[(size_t)(c0 + 1) * HW_];
            unsigned pk = (unsigned)__half_as_ushort(__float2half_rn(v0))
                        | ((unsigned)__half_as_ushort(__float2half_rn(v1)) << 16);
            int c16 = widx >> 2, rem = widx & 3;
            zw[px * 132 + (((c16 ^ key) << 2) | rem)] = pk;
        }
    }
    __syncthreads();

    unsigned b1[2] = { 0xFFFFFFFFu, 0xFFFFFFFFu };
    unsigned b2[2] = { 0xFFFFFFFFu, 0xFFFFFFFFu };

    // A-frag base (ushort index): code-in-chunk row = w*64 + mt*32 + (l&31)
    const unsigned short* ab = cbh + ((size_t)(w * 64 + (l & 31)) * 16 + (l >> 5) * 8);
    // step s (0..63): offset = (s&15)*16384 + (s>>4)*4096 ; mt stride 512
    short rowmap = (short)((l >> 5) << 2);       // +4*(lane>>5) in C/D rows
    half8 pf[2][2];
#pragma unroll
    for (int i = 0; i < 2; i++) {
        const unsigned short* s = ab + (i & 15) * 16384 + (i >> 4) * 4096;
        pf[i][0] = *(const half8*)(s);
        pf[i][1] = *(const half8*)(s + 512);
    }

    int bkey = ((l & 31) >> 3) & 3;
    int prow0 = (l & 31) * 132;

    for (int chunk = 0; chunk < 4; chunk++) {
        float16 acc[2][2];
#pragma unroll
        for (int mt = 0; mt < 2; mt++)
#pragma unroll
            for (int nt = 0; nt < 2; nt++)
#pragma unroll
                for (int r = 0; r < 16; r++) acc[mt][nt][r] = 0.f;

#pragma unroll
        for (int kk = 0; kk < 16; kk++) {
            int step = chunk * 16 + kk;
            int buf = step & 1;
            half8 a0 = pf[buf][0], a1 = pf[buf][1];
            int ns = step + 2; if (ns > 63) ns = 63;
            {
                const unsigned short* s = ab + (ns & 15) * 16384 + (ns >> 4) * 4096;
                pf[buf][0] = *(const half8*)(s);
                pf[buf][1] = *(const half8*)(s + 512);
            }
            half8 bz[2];
#pragma unroll
            for (int nt = 0; nt < 2; nt++) {
                int c16 = kk * 2 + (l >> 5);
                int word = (nt * 32 * 132 + prow0) + ((c16 ^ bkey) << 2);
                bz[nt] = *(const half8*)((const char*)zw + (size_t)word * 4);
            }
            acc[0][0] = __builtin_amdgcn_mfma_f32_32x32x16_f16(a0, bz[0], acc[0][0], 0, 0, 0);
            acc[0][1] = __builtin_amdgcn_mfma_f32_32x32x16_f16(a0, bz[1], acc[0][1], 0, 0, 0);
            acc[1][0] = __builtin_amdgcn_mfma_f32_32x32x16_f16(a1, bz[0], acc[1][0], 0, 0, 0);
            acc[1][1] = __builtin_amdgcn_mfma_f32_32x32x16_f16(a1, bz[1], acc[1][1], 0, 0, 0);
        }

        // fold into packed-key top-2 (s' = sc+0.25 - 2^-9*acc, positive)
#pragma unroll
        for (int mt = 0; mt < 2; mt++)
#pragma unroll
            for (int r = 0; r < 16; r++) {
                int scode = chunk * 256 + w * 64 + mt * 32
                          + (r & 3) + ((r >> 2) << 3) + rowmap;
                float sv = scs[scode];
                unsigned emb = (unsigned)((chunk << 5) | (mt << 4) | r);
#pragma unroll
                for (int nt = 0; nt < 2; nt++) {
                    float s = fmaf(-0.001953125f, acc[mt][nt][r], sv);
                    unsigned key = (__float_as_uint(s) & 0xFFFFFF80u) | emb;
                    b2[nt] = umin_(b2[nt], umax_(b1[nt], key));
                    b1[nt] = umin_(b1[nt], key);
                }
            }
    }

    // decode + lane-pair merge (l, l^32: same pixel, disjoint code rows)
#pragma unroll
    for (int nt = 0; nt < 2; nt++) {
        unsigned e1 = b1[nt] & 127u;
        float f1 = __uint_as_float(b1[nt] & 0xFFFFFF80u);
        float f2 = __uint_as_float(b2[nt] & 0xFFFFFF80u);
        int idx = (int)(e1 >> 5) * 256 + w * 64 + (int)((e1 >> 4) & 1) * 32
                + (int)(e1 & 3) + (int)(((e1 >> 2) & 3) << 3) + (int)rowmap;

        float of1 = __shfl_xor(f1, 32, 64);
        int   oi  = __shfl_xor(idx, 32, 64);
        float of2 = __shfl_xor(f2, 32, 64);
        if (of1 < f1 || (of1 == f1 && oi < idx)) {
            f2 = fminf(f1, of2); f1 = of1; idx = oi;
        } else {
            f2 = fminf(f2, of1);
        }

        if (l < 32) {
            int e = (w * 64 + nt * 32 + l) * 4;
            ex[e + 0] = f1;
            ex[e + 1] = f2;
            ((int*)ex)[e + 2] = idx;
        }
    }
    __syncthreads();
    if (t < 64) {
        float cb1 = FLT_BIG, cb2 = FLT_BIG; int cj1 = 0;
#pragma unroll
        for (int wv = 0; wv < 4; wv++) {
            int e = (wv * 64 + t) * 4;
            float nb1 = ex[e + 0];
            float nb2 = ex[e + 1];
            int   nj1 = ((int*)ex)[e + 2];
            if (nb1 < cb1 || (nb1 == cb1 && nj1 < cj1)) {
                cb2 = fminf(cb1, nb2); cb1 = nb1; cj1 = nj1;
            } else {
                cb2 = fminf(cb2, nb1);
            }
        }
        int n = n0 + t;
        s1o[n] = cb1; s2o[n] = cb2; i1o[n] = cj1;
    }
}

// ---------------------------------------------------------------------------
// Flag pass: commit clear winners; compact near-ties.
// ---------------------------------------------------------------------------
__global__ void flag_kernel(const float* __restrict__ s1, const float* __restrict__ s2,
                            const int* __restrict__ i1,
                            int* __restrict__ fidx, float* __restrict__ out_idx,
                            int* __restrict__ list, int* __restrict__ count) {
    int n = blockIdx.x * 256 + threadIdx.x;
    int j = i1[n];
    fidx[n] = j;
    out_idx[n] = (float)j;
    if (s2[n] - s1[n] < GAP_T) {
        int pos = atomicAdd(count, 1);
        list[pos] = n;
    }
}

// ---------------------------------------------------------------------------
// Exact refine (PASSED r4 semantics, unchanged except grid stride 8192):
// wave per flagged pixel, fp64 dot via cbT, then reference-quantized fp32:
//   dq = fp32( fp32(sz + sc[k]) - 2*fp32(dot) ), first-index argmin.
// Grid 2048 blocks -> 32 waves/CU -> L2 latency hidden.
// ---------------------------------------------------------------------------
__global__ void refine_kernel(const float* __restrict__ z, const float* __restrict__ cbT,
                              const float* __restrict__ sz, const float* __restrict__ sc,
                              const int* __restrict__ list, const int* __restrict__ count,
                              int* __restrict__ fidx, float* __restrict__ out_idx) {
    __shared__ double zd[4][256];
    int w = threadIdx.x >> 6, l = threadIdx.x & 63;
    int cnt = *count;
    if (cnt > 65536) cnt = 65536;
    for (int ii = blockIdx.x * 4 + w; ii < cnt; ii += 8192) {
        int n = list[ii];
        const float* zp = z + (size_t)(n >> 12) * CHW_ + (n & 4095);
#pragma unroll
        for (int j = 0; j < 4; j++)
            zd[w][l * 4 + j] = (double)zp[(size_t)(l * 4 + j) * HW_];
        asm volatile("s_waitcnt lgkmcnt(0)" ::: "memory");
        double acc[16];
#pragma unroll
        for (int a = 0; a < 16; a++) acc[a] = 0.0;
        for (int c = 0; c < 256; c++) {
            double zc = zd[w][c];
            const float* cp = cbT + (size_t)c * K_ + l * 4;
#pragma unroll
            for (int it = 0; it < 4; it++) {
                float4 cv = *(const float4*)(cp + it * 256);
                acc[it * 4 + 0] += zc * (double)cv.x;
                acc[it * 4 + 1] += zc * (double)cv.y;
                acc[it * 4 + 2] += zc * (double)cv.z;
                acc[it * 4 + 3] += zc * (double)cv.w;
            }
        }
        float szv = sz[n];
        float best = FLT_BIG; int bidx = K_;
#pragma unroll
        for (int it = 0; it < 4; it++)
#pragma unroll
            for (int s = 0; s < 4; s++) {
                int k = it * 256 + l * 4 + s;
                float dotf = (float)acc[it * 4 + s];
                float dq = (szv + sc[k]) - 2.0f * dotf;
                if (dq < best || (dq == best && k < bidx)) { best = dq; bidx = k; }
            }
#pragma unroll
        for (int off = 32; off > 0; off >>= 1) {
            float ob = __shfl_xor(best, off, 64);
            int   oj = __shfl_xor(bidx, off, 64);
            if (ob < best || (ob == best && oj < bidx)) { best = ob; bidx = oj; }
        }
        if (l == 0) { fidx[n] = bidx; out_idx[n] = (float)bidx; }
        asm volatile("s_waitcnt lgkmcnt(0)" ::: "memory");
    }
}

// ---------------------------------------------------------------------------
// Gather zq -> NCHW output + loss partials (PASSED r2/r4)
// ---------------------------------------------------------------------------
__global__ void output_kernel(const float* __restrict__ z, const float* __restrict__ cb,
                              const int* __restrict__ fidx,
                              float* __restrict__ out0, double* __restrict__ partials) {
    __shared__ double red[256];
    int t = threadIdx.x;
    int blk = blockIdx.x;
    int n0 = blk * 64;
    int batch = n0 >> 12, s0 = n0 & 4095;
    const float* zbase = z + (size_t)batch * CHW_ + s0;
    float* obase = out0 + (size_t)batch * CHW_ + s0;
    double sum = 0.0;
#pragma unroll 4
    for (int r = 0; r < 64; r++) {
        int f = r * 256 + t;
        int c = f >> 6, i = f & 63;
        int idx = fidx[n0 + i];
        float q  = cb[(size_t)idx * C_ + c];
        float zv = zbase[(size_t)c * HW_ + i];
        obase[(size_t)c * HW_ + i] = q;
        float d = q - zv;
        sum += (double)d * (double)d;
    }
    red[t] = sum;
    __syncthreads();
    for (int s = 128; s > 0; s >>= 1) {
        if (t < s) red[t] += red[t + s];
        __syncthreads();
    }
    if (t == 0) partials[blk] = red[0];
}

__global__ void loss_kernel(const double* __restrict__ partials, float* __restrict__ out_loss) {
    __shared__ double red[256];
    int t = threadIdx.x;
    double s = 0.0;
    for (int r = t; r < 1024; r += 256) s += partials[r];
    red[t] = s;
    __syncthreads();
    for (int k = 128; k > 0; k >>= 1) {
        if (t < k) red[t] += red[t + k];
        __syncthreads();
    }
    if (t == 0) *out_loss = (float)(0.75 * red[0] / 16777216.0);
}

// ---------------------------------------------------------------------------
extern "C" void kernel_launch(void* const* d_in, const int* in_sizes, int n_in,
                              void* d_out, int out_size, void* d_ws, size_t ws_size,
                              hipStream_t stream) {
    const float* z  = (const float*)d_in[0];
    const float* cb = (const float*)d_in[1];

    float* out0     = (float*)d_out;
    float* out_idx  = out0 + (size_t)16777216;
    float* out_loss = out0 + (size_t)16842752;

    char* w = (char*)d_ws;
    double* partials = (double*)w;                       //       0 .. 8192
    float*  sc   = (float*)(w + 8192);                   //    8192 .. 12288
    float*  sz   = (float*)(w + 12288);                  //   12288 .. 274432
    float*  s1   = (float*)(w + 274432);
    float*  s2   = (float*)(w + 536576);
    int*    i1   = (int*)  (w + 798720);
    int*    fidx = (int*)  (w + 1060864);
    int*    count= (int*)  (w + 1323008);
    int*    list = (int*)  (w + 1323264);                // 256 KB
    unsigned short* cbh = (unsigned short*)(w + 1585408);// 512 KB
    float*  cbT  = (float*)(w + 2109952);                // 1 MB -> ends ~3.1 MB

    hipMemsetAsync(count, 0, 4, stream);
    sz_kernel    <<<256,  256, 0, stream>>>(z, sz);
    sc_kernel    <<<4,    256, 0, stream>>>(cb, sc);
    cbh_prep     <<<1024, 256, 0, stream>>>(cb, cbh);
    cbT_prep     <<<256, 1024, 0, stream>>>(cb, cbT);
    score_kernel <<<1024, 256, 0, stream>>>(z, cbh, sc, s1, s2, i1);
    flag_kernel  <<<256,  256, 0, stream>>>(s1, s2, i1, fidx, out_idx, list, count);
    refine_kernel<<<2048, 256, 0, stream>>>(z, cbT, sz, sc, list, count, fidx, out_idx);
    output_kernel<<<1024, 256, 0, stream>>>(z, cb, fidx, out0, partials);
    loss_kernel  <<<1,    256, 0, stream>>>(partials, out_loss);
}